// Round 16
// baseline (106.005 us; speedup 1.0000x reference)
//
#include <hip/hip_runtime.h>
#include <hip/hip_fp16.h>
#include <cstdint>
#include <cstddef>

// ---------------------------------------------------------------------------
// VectorQuantizerEMA on MI355X.  B=8,S=2048,D=256,K=4096 -> N=16384 tokens.
//   1) vq_split (fused z+codebook) -> fp16 packs, norms, |c|^2, norm maxima
//   2) vq_scan R15: 32 tg x 32 es (1024 blocks, 512 thr). Wave holds SIXTY-
//      FOUR tokens (zfrP/zfrQ = 128 VGPR) -> each staged A-fragment ds_read
//      feeds 2 MFMAs (accP/accQ independent chains). Halves the LDS pipe
//      (was 1 read/MFMA = 20.5us of the measured 45; serial pipe sum matched
//      measurement, LDS was the largest term). One staging barrier, setprio.
//   3) vq_merge: decode 32 records/token, window + exact fp64 rescore ->
//      argmin (winner row in regs); out0/out_idx; loss partials; count
//      histogram + bucket write
//   4) vq_segsum: 8 waves/entry over slots row, fused EMA weight write
//   5) new_count normalize + loss finalize
// History: R1 atomic chains. R5 32x32 scan. R6 split_c chain. R7 counting
// sort. R8 segsum parallel. R9 zfr residency. R10 packed keys. R12 one-
// barrier free-run. R13 deferral regressed. R14 setprio+fusions (102.6us,
// scan 45.4). R15: 2 token-blocks/wave -> 0.5 ds_read per MFMA.
// ---------------------------------------------------------------------------

#define N_TOK 16384
#define DIM   256
#define K_CB  4096

typedef _Float16 h8    __attribute__((ext_vector_type(8)));
typedef float    f32x4 __attribute__((ext_vector_type(4)));
typedef float    f32x16 __attribute__((ext_vector_type(16)));

// ---- ws layout (bytes) ----
#define WS_ZF      0u            // N_TOK * 512B fp16 frag layout = 8 MB
#define WS_CP      8388608u      // K_CB * 512B fp16 rows         = 2 MB
#define WS_CN      10485760u     // K_CB fp32 |c|^2               = 16 KB
#define WS_NRM     10502144u     // N_TOK float2                  = 128 KB
#define WS_CAND    10633216u     // N_TOK * 32 float2             = 4 MB
#define WS_COUNT   14827520u     // K_CB int                      = 16 KB
#define WS_SLOTS   14843904u     // K_CB * 1024 int               = 16 MB
#define WS_NACC    31621120u     // K_CB float                    = 16 KB
#define WS_NB      31637504u     // 2 floats (+pad 16B)
#define WS_LPART   31637520u     // 4096 float
#define WS_MPART   31653904u     // 4096 float
#define WS_NBPART  31670288u     // 1024 float2 = 8 KB

__device__ __forceinline__ void gload_lds16(const void* g, void* l) {
  __builtin_amdgcn_global_load_lds(
      (const __attribute__((address_space(1))) uint32_t*)g,
      (__attribute__((address_space(3))) uint32_t*)l, 16, 0, 0);
}

// ---- 1: fused split: blocks 0-2047 = z path, 2048-3071 = codebook path ----
__global__ void vq_split(const float* __restrict__ z, const float* __restrict__ cb,
                         unsigned short* __restrict__ zf, float2* __restrict__ nrm,
                         unsigned short* __restrict__ cp1, float* __restrict__ cn1,
                         float2* __restrict__ nbpart) {
  __shared__ float sm1[4], sm2[4];
  if (blockIdx.x < 2048) {
    // ---- z split: fragment-layout fp16 + per-token norms ----
    int t = blockIdx.x * 256 + threadIdx.x;     // 524288 threads, 32 per token
    int tok = t >> 5, c = t & 31;
    const float4* zp = reinterpret_cast<const float4*>(z) + (size_t)tok * 64 + c * 2;
    float4 va = zp[0], vb = zp[1];
    float x[8] = {va.x, va.y, va.z, va.w, vb.x, vb.y, vb.z, vb.w};
    union { _Float16 h[8]; uint4 u; } a;
    float s1 = 0.f, s2 = 0.f;
#pragma unroll
    for (int i = 0; i < 8; ++i) {
      _Float16 h1 = (_Float16)x[i];
      float lo = (x[i] - (float)h1) * 2048.0f;
      a.h[i] = h1;
      s1 += (float)h1 * (float)h1;
      s2 += lo * lo;
    }
    size_t off = (size_t)(tok >> 7) * 65536u + (size_t)(c >> 1) * 4096u
               + (size_t)(tok & 127) * 32u + (size_t)(c & 1) * 16u;
    *reinterpret_cast<uint4*>((unsigned char*)zf + off) = a.u;
#pragma unroll
    for (int o = 1; o < 32; o <<= 1) { s1 += __shfl_xor(s1, o); s2 += __shfl_xor(s2, o); }
    if (c == 0) nrm[tok] = make_float2(sqrtf(s1), sqrtf(s2));
  } else {
    // ---- codebook split: h1 rows + |c|^2 + per-block norm maxima ----
    int bid = blockIdx.x - 2048;
    int w = threadIdx.x >> 6, l = threadIdx.x & 63;
    int row = bid * 4 + w;
    float4 v = reinterpret_cast<const float4*>(cb)[row * 64 + l];
    float x[4] = {v.x, v.y, v.z, v.w};
    union { _Float16 h[4]; ushort4 u; } a;
    double ss = 0.0;
    float s1 = 0.f, s2 = 0.f;
#pragma unroll
    for (int i = 0; i < 4; ++i) {
      _Float16 h1 = (_Float16)x[i];
      float lo = (x[i] - (float)h1) * 2048.0f;
      a.h[i] = h1;
      s1 += (float)h1 * (float)h1;
      s2 += lo * lo;
      ss += (double)x[i] * (double)x[i];
    }
    reinterpret_cast<ushort4*>(cp1)[row * 64 + l] = a.u;
    for (int off = 1; off < 64; off <<= 1) {
      s1 += __shfl_xor(s1, off); s2 += __shfl_xor(s2, off); ss += __shfl_xor(ss, off);
    }
    if (l == 0) {
      cn1[row] = (float)ss;
      sm1[w] = s1; sm2[w] = s2;
    }
    __syncthreads();
    if (threadIdx.x == 0) {
      float m1 = fmaxf(fmaxf(sm1[0], sm1[1]), fmaxf(sm1[2], sm1[3]));
      float m2 = fmaxf(fmaxf(sm2[0], sm2[1]), fmaxf(sm2[2], sm2[3]));
      nbpart[bid] = make_float2(sqrtf(m1), sqrtf(m2));
    }
  }
}

// ---- 1c: reduce 1024 per-block maxima -> nb[0..1] --------------------------
__global__ void vq_nb_reduce(const float2* __restrict__ nbpart, float* __restrict__ nb) {
  __shared__ float r1[256], r2[256];
  int tid = threadIdx.x;
  float m1 = 0.f, m2 = 0.f;
  for (int i = tid; i < 1024; i += 256) {
    float2 p = nbpart[i];
    m1 = fmaxf(m1, p.x); m2 = fmaxf(m2, p.y);
  }
  r1[tid] = m1; r2[tid] = m2; __syncthreads();
  for (int s = 128; s > 0; s >>= 1) {
    if (tid < s) { r1[tid] = fmaxf(r1[tid], r1[tid + s]); r2[tid] = fmaxf(r2[tid], r2[tid + s]); }
    __syncthreads();
  }
  if (tid == 0) { nb[0] = r1[0]; nb[1] = r2[0]; }
}

// ---- 2: distance scan: 64 tokens/wave, 0.5 ds_read per MFMA ----------------
// Block: 512 thr = 8 waves; wave w owns tokens tok0+w*64 .. +63 (P = first
// 32 in zfrP, Q = next 32 in zfrQ; both volatile-asm resident). CB slice 128
// entries x 512B in 66KB dynamic LDS (XOR-32 swizzle via pre-swizzled global
// src), ONE barrier, then free-run: per kt ONE af ds_read feeds mfma(accP)
// AND mfma(accQ). acc = -d/2 <= 0: min-uint(acc bits) = min-d.
__global__ __launch_bounds__(512, 1) void vq_scan(
    const unsigned short* __restrict__ zf, const unsigned short* __restrict__ cp,
    const float* __restrict__ cn1, const float2* __restrict__ nrm,
    float2* __restrict__ cand) {
  extern __shared__ __align__(1024) unsigned char lds[];   // 66048 bytes
  unsigned char* cbl = lds;                                // 64 KB
  float* cnl = reinterpret_cast<float*>(lds + 65536);      // 512 B

  const int bid  = blockIdx.x;
  const int wgid = (bid & 7) * 128 + (bid >> 3);   // bijective: 1024 = 8*128
  const int tg   = wgid >> 5;                      // 0..31 token group (512 tok)
  const int es   = wgid & 31;                      // 0..31 entry split (128 e)
  const int tok0 = tg * 512;
  const int e0b  = es * 128;

  const int tx = threadIdx.x;
  const int w = tx >> 6, l = tx & 63;
  const int r = l & 31, h = l >> 5;

  // Z fragments: P and Q token-blocks, 32 x h8 = 128 VGPRs, forced resident
  const unsigned char* zgP = (const unsigned char*)zf
      + (size_t)(tg * 4 + (w >> 1)) * 65536u
      + (unsigned)((((w & 1) * 64 + r) * 32) + h * 16);
  h8 zfrP[16], zfrQ[16];
#pragma unroll
  for (int kt = 0; kt < 16; ++kt) {
    const void* pP = zgP + kt * 4096;
    const void* pQ = zgP + kt * 4096 + 1024;
    asm volatile("global_load_dwordx4 %0, %1, off" : "=v"(zfrP[kt]) : "v"(pP));
    asm volatile("global_load_dwordx4 %0, %1, off" : "=v"(zfrQ[kt]) : "v"(pQ));
  }
  const int twP = tok0 + w * 64 + r;
  float znrP = nrm[twP].x, znrQ = nrm[twP + 32].x;
  const float znP = znrP * znrP, znQ = znrQ * znrQ;

  // stage whole CB slice (8 rounds x 8KB) + cn row; ONE barrier
  const unsigned char* cpb = (const unsigned char*)cp;
#pragma unroll
  for (int j = 0; j < 8; ++j) {
    int row = j * 16 + w * 2 + (l >> 5);           // each of 128 rows once
    int lc  = (l & 31) ^ (row & 31);               // logical chunk (swizzled)
    gload_lds16(cpb + (size_t)(e0b + row) * 512 + lc * 16,
                &cbl[(j * 16 + w * 2) * 512]);     // wave-uniform dst
  }
  if (tx < 32)
    gload_lds16((const unsigned char*)cn1 + (size_t)e0b * 4 + tx * 16, cnl);
  __syncthreads();   // vmcnt(0): CB slice + cn + zfr all landed

  unsigned loP = 0xFFFFFFFFu, hiP = 0xFFFFFFFFu;
  unsigned loQ = 0xFFFFFFFFu, hiQ = 0xFFFFFFFFu;
#pragma unroll
  for (int t = 0; t < 4; ++t) {
    f32x16 accP, accQ;
#pragma unroll
    for (int g = 0; g < 4; ++g) {
      f32x4 cnv = *reinterpret_cast<const f32x4*>(&cnl[t * 32 + g * 8 + 4 * h]);
#pragma unroll
      for (int q = 0; q < 4; ++q) {
        accP[g * 4 + q] = -0.5f * (znP + cnv[q]);
        accQ[g * 4 + q] = -0.5f * (znQ + cnv[q]);
      }
    }
    __builtin_amdgcn_s_setprio(1);
#pragma unroll
    for (int kt = 0; kt < 16; ++kt) {
      int sc = (kt * 2 + h) ^ r;
      h8 af = *reinterpret_cast<const h8*>(&cbl[t * 16384 + r * 512 + sc * 16]);
      accP = __builtin_amdgcn_mfma_f32_32x32x16_f16(af, zfrP[kt], accP, 0, 0, 0);
      accQ = __builtin_amdgcn_mfma_f32_32x32x16_f16(af, zfrQ[kt], accQ, 0, 0, 0);
    }
    __builtin_amdgcn_s_setprio(0);
#pragma unroll
    for (int i = 0; i < 16; ++i) {
      unsigned eloc = (unsigned)(t * 32 + ((i & 3) + 8 * (i >> 2) + 4 * h));
      unsigned keyP = (__float_as_uint(accP[i]) & 0xFFFFFF00u) | eloc;
      unsigned keyQ = (__float_as_uint(accQ[i]) & 0xFFFFFF00u) | eloc;
      unsigned mxP = loP > keyP ? loP : keyP;
      loP = loP < keyP ? loP : keyP;
      hiP = hiP < mxP ? hiP : mxP;
      unsigned mxQ = loQ > keyQ ? loQ : keyQ;
      loQ = loQ < keyQ ? loQ : keyQ;
      hiQ = hiQ < mxQ ? hiQ : mxQ;
    }
  }

  // merge the two lane-halves, write two float2 records (keys in bits)
  {
    unsigned oloP = __shfl_xor(loP, 32), ohiP = __shfl_xor(hiP, 32);
    unsigned mxP = loP > oloP ? loP : oloP;
    loP = loP < oloP ? loP : oloP;
    hiP = hiP < ohiP ? hiP : ohiP;
    hiP = hiP < mxP ? hiP : mxP;
    unsigned oloQ = __shfl_xor(loQ, 32), ohiQ = __shfl_xor(hiQ, 32);
    unsigned mxQ = loQ > oloQ ? loQ : oloQ;
    loQ = loQ < oloQ ? loQ : oloQ;
    hiQ = hiQ < ohiQ ? hiQ : ohiQ;
    hiQ = hiQ < mxQ ? hiQ : mxQ;
    if (h == 0) {
      cand[(size_t)twP * 32 + es] =
          make_float2(__uint_as_float(loP), __uint_as_float(hiP));
      cand[(size_t)(twP + 32) * 32 + es] =
          make_float2(__uint_as_float(loQ), __uint_as_float(hiQ));
    }
  }
}

// ---- 3: decode keys, window + exact fp64 rescore; bucket write -------------
__global__ void vq_merge(
    const float2* __restrict__ cand, const float* __restrict__ z,
    const float* __restrict__ mask, const float* __restrict__ codebook,
    const float2* __restrict__ nrm, const float* __restrict__ nb,
    float* __restrict__ out0, float* __restrict__ out_idx,
    int* __restrict__ count, int* __restrict__ slots,
    float* __restrict__ loss_part, float* __restrict__ mask_part) {
  __shared__ float ls[4], ms[4];
  int w = threadIdx.x >> 6, l = threadIdx.x & 63;
  int token = blockIdx.x * 4 + w;

  float2 rec = cand[(size_t)token * 32 + (l & 31)];
  unsigned k1 = __float_as_uint(rec.x), k2 = __float_as_uint(rec.y);
  float rv1 = -2.0f * __uint_as_float(k1 & 0xFFFFFF00u);
  float rv2 = -2.0f * __uint_as_float(k2 & 0xFFFFFF00u);
  int   ri1 = (l & 31) * 128 + (int)(k1 & 0xFFu);
  int   ri2 = (l & 31) * 128 + (int)(k2 & 0xFFu);
  float m_a = rv1;
  for (int o = 1; o < 32; o <<= 1) m_a = fminf(m_a, __shfl_xor(m_a, o));

  // rigorous fp16-GEMM error bound + key-truncation widening
  float2 nh = nrm[token];
  float NB1 = nb[0], NB2 = nb[1];
  float E = 2.0f * ((nh.x * NB2 + nh.y * NB1) * (1.0f / 2048.0f)
                    + nh.y * NB2 * (1.0f / 4194304.0f));
  float thr = m_a * 1.0001f + 2.0f * E * 1.05f + 0.1f;

  float4 zv = reinterpret_cast<const float4*>(z)[(size_t)token * 64 + l];

  unsigned long long c1 = __ballot((l < 32) && (rv1 <= thr));
  unsigned long long c2 = __ballot((l < 32) && (rv2 <= thr));
  double bd = 1e300; int bi = 0x7fffffff;
  float4 cvb = make_float4(0.f, 0.f, 0.f, 0.f);
  while (c1 | c2) {
    int k;
    if (c1) { int s = __ffsll(c1) - 1; c1 &= c1 - 1; k = __shfl(ri1, s); }
    else    { int s = __ffsll(c2) - 1; c2 &= c2 - 1; k = __shfl(ri2, s); }
    float4 cv = reinterpret_cast<const float4*>(codebook)[(size_t)k * 64 + l];
    double d0 = (double)zv.x - cv.x, d1 = (double)zv.y - cv.y;
    double d2 = (double)zv.z - cv.z, d3 = (double)zv.w - cv.w;
    double dd = d0 * d0 + d1 * d1 + d2 * d2 + d3 * d3;
    for (int o = 1; o < 64; o <<= 1) dd += __shfl_xor(dd, o);
    if (dd < bd || (dd == bd && k < bi)) { bd = dd; bi = k; cvb = cv; }
  }

  reinterpret_cast<float4*>(out0)[(size_t)token * 64 + l] = cvb;  // quantized

  float mk = mask[token];
  if (l == 0) {
    out_idx[token] = (float)bi;
    int pos = atomicAdd(&count[bi], 1);            // cursor + histogram in one
    if (pos < 1024) slots[(size_t)bi * 1024 + pos] = token;
    ls[w] = mk * (float)bd * (1.0f / 256.0f);      // exact sum (z-q)^2
    ms[w] = mk;
  }
  __syncthreads();
  if (threadIdx.x == 0) {
    loss_part[blockIdx.x] = ls[0] + ls[1] + ls[2] + ls[3];
    mask_part[blockIdx.x] = ms[0] + ms[1] + ms[2] + ms[3];
  }
}

// ---- 4: segmented sum over slot rows: 8 waves/entry, 2-deep, LDS reduce ----
__global__ __launch_bounds__(512) void vq_segsum(
    const int* __restrict__ count, const int* __restrict__ slots,
    const float* __restrict__ z, const float* __restrict__ mask,
    const float* __restrict__ ew,
    float* __restrict__ out_weight, float* __restrict__ nacc) {
  __shared__ float4 red[8][64];
  __shared__ float nas[8];
  const int k = blockIdx.x;
  const int w = threadIdx.x >> 6, l = threadIdx.x & 63;
  int e = count[k]; if (e > 1024) e = 1024;
  const int* seg = slots + (size_t)k * 1024;
  const float4* z4 = reinterpret_cast<const float4*>(z);

  float ax = 0.f, ay = 0.f, az = 0.f, aw = 0.f, na = 0.f;
  int i = w;
  for (; i + 8 < e; i += 16) {
    int t0 = seg[i], t1 = seg[i + 8];
    float mk0 = mask[t0], mk1 = mask[t1];
    float4 a4 = z4[(size_t)t0 * 64 + l];
    float4 b4 = z4[(size_t)t1 * 64 + l];
    ax += mk0 * a4.x + mk1 * b4.x;
    ay += mk0 * a4.y + mk1 * b4.y;
    az += mk0 * a4.z + mk1 * b4.z;
    aw += mk0 * a4.w + mk1 * b4.w;
    na += mk0 + mk1;
  }
  if (i < e) {
    int t0 = seg[i];
    float mk0 = mask[t0];
    float4 a4 = z4[(size_t)t0 * 64 + l];
    ax += mk0 * a4.x; ay += mk0 * a4.y; az += mk0 * a4.z; aw += mk0 * a4.w;
    na += mk0;
  }
  red[w][l] = make_float4(ax, ay, az, aw);
  if (l == 0) nas[w] = na;
  __syncthreads();

  if (w == 0) {
    float4 a = red[0][l];
#pragma unroll
    for (int j = 1; j < 8; ++j) {
      float4 b = red[j][l];
      a.x += b.x; a.y += b.y; a.z += b.z; a.w += b.w;
    }
    float4 e4 = reinterpret_cast<const float4*>(ew)[(size_t)k * 64 + l];
    float4 o;
    o.x = 0.99f * e4.x + 0.01f * a.x;
    o.y = 0.99f * e4.y + 0.01f * a.y;
    o.z = 0.99f * e4.z + 0.01f * a.z;
    o.w = 0.99f * e4.w + 0.01f * a.w;
    reinterpret_cast<float4*>(out_weight)[(size_t)k * 64 + l] = o;
    if (l == 0) {
      float nn = 0.f;
#pragma unroll
      for (int j = 0; j < 8; ++j) nn += nas[j];
      nacc[k] = nn;
    }
  }
}

// ---- 5: new_count normalize + deterministic loss reduce --------------------
__global__ void vq_finish_count(const float* __restrict__ ec, const float* __restrict__ nacc,
                                const float* __restrict__ loss_part,
                                const float* __restrict__ mask_part,
                                float* __restrict__ out_count, float* __restrict__ out_loss) {
  __shared__ float nc_s[K_CB];
  __shared__ float red[256];
  int tid = threadIdx.x;
  float part = 0.f;
  for (int i = tid; i < K_CB; i += 256) {
    float nc = 0.99f * ec[i] + 0.01f * nacc[i];
    nc_s[i] = nc; part += nc;
  }
  red[tid] = part; __syncthreads();
  for (int s = 128; s > 0; s >>= 1) { if (tid < s) red[tid] += red[tid + s]; __syncthreads(); }
  float total = red[0];
  float scale = total / (total + (float)K_CB * 1e-5f);
  for (int i = tid; i < K_CB; i += 256) out_count[i] = (nc_s[i] + 1e-5f) * scale;
  __syncthreads();

  float ln = 0.f, lm = 0.f;
  for (int i = tid; i < 4096; i += 256) { ln += loss_part[i]; lm += mask_part[i]; }
  red[tid] = ln; __syncthreads();
  for (int s = 128; s > 0; s >>= 1) { if (tid < s) red[tid] += red[tid + s]; __syncthreads(); }
  ln = red[0]; __syncthreads();
  red[tid] = lm; __syncthreads();
  for (int s = 128; s > 0; s >>= 1) { if (tid < s) red[tid] += red[tid + s]; __syncthreads(); }
  lm = red[0];
  if (tid == 0) out_loss[0] = 2.5f * ln / lm;      // 10 * 0.25 * num/den
}

extern "C" void kernel_launch(void* const* d_in, const int* in_sizes, int n_in,
                              void* d_out, int out_size, void* d_ws, size_t ws_size,
                              hipStream_t stream) {
  const float* z          = (const float*)d_in[0];
  const float* mask       = (const float*)d_in[1];
  const float* codebook   = (const float*)d_in[2];
  const float* ema_count  = (const float*)d_in[3];
  const float* ema_weight = (const float*)d_in[4];

  float* out        = (float*)d_out;
  float* out0       = out;                         // 4194304
  float* out_idx    = out + 4194304;               // 16384
  float* out_loss   = out + 4210688;               // 1
  float* out_count  = out + 4210689;               // 4096
  float* out_weight = out + 4214785;               // 1048576

  char* ws = (char*)d_ws;
  unsigned short* zf  = (unsigned short*)(ws + WS_ZF);
  unsigned short* cp1 = (unsigned short*)(ws + WS_CP);
  float*  cn1    = (float*) (ws + WS_CN);
  float2* nrm    = (float2*)(ws + WS_NRM);
  float2* cand   = (float2*)(ws + WS_CAND);
  int*    count  = (int*)   (ws + WS_COUNT);
  int*    slots  = (int*)   (ws + WS_SLOTS);
  float*  nacc   = (float*) (ws + WS_NACC);
  float*  nbmax  = (float*) (ws + WS_NB);
  float*  lpart  = (float*) (ws + WS_LPART);
  float*  mpart  = (float*) (ws + WS_MPART);
  float2* nbpart = (float2*)(ws + WS_NBPART);

  (void)hipFuncSetAttribute((const void*)vq_scan,
                            hipFuncAttributeMaxDynamicSharedMemorySize, 66048);
  (void)hipMemsetAsync(ws + WS_COUNT, 0, 16384, stream);   // count only

  vq_split<<<3072, 256, 0, stream>>>(z, codebook, zf, nrm, cp1, cn1, nbpart);
  vq_nb_reduce<<<1, 256, 0, stream>>>(nbpart, nbmax);
  vq_scan<<<1024, 512, 66048, stream>>>(zf, cp1, cn1, nrm, cand);
  vq_merge<<<4096, 256, 0, stream>>>(cand, z, mask, codebook, nrm, nbmax,
                                     out0, out_idx, count, slots, lpart, mpart);
  vq_segsum<<<4096, 512, 0, stream>>>(count, slots, z, mask, ema_weight,
                                      out_weight, nacc);
  vq_finish_count<<<1, 256, 0, stream>>>(ema_count, nacc, lpart, mpart,
                                         out_count, out_loss);
}

// Round 17
// 101.552 us; speedup vs baseline: 1.0438x; 1.0438x over previous
//
#include <hip/hip_runtime.h>
#include <hip/hip_fp16.h>
#include <cstdint>
#include <cstddef>

// ---------------------------------------------------------------------------
// VectorQuantizerEMA on MI355X.  B=8,S=2048,D=256,K=4096 -> N=16384 tokens.
//   1) vq_split (fused z+codebook) -> fp16 packs, norms, |c|^2, norm maxima
//   2) vq_scan (R14 form, verified 45.4us): 64 tg x 32 es, 512 thr, whole
//      128-entry CB slice in 66KB dynamic LDS, ONE barrier, free-run 4 tiles
//      x 16 mfma_32x32x16 + packed-key select, setprio around MFMA chain.
//   3) vq_merge: fused nb max-reduce (nbpart 8KB, L2-hit) + decode 32
//      records/token, window + exact fp64 rescore -> argmin (winner row in
//      regs); out0/out_idx; loss partials; count histogram + bucket write
//   4) vq_segsum: 8 waves/entry over slots row, fused EMA weight write
//   5) new_count normalize + loss finalize
// History: R1 atomic chains. R5 32x32 scan. R6 split_c chain. R7 counting
// sort. R8 segsum parallel. R9 zfr residency. R10 packed keys. R12 one-
// barrier free-run. R13 deferral regressed (VGPR). R14 setprio+fusions
// (102.6us, scan 45.4, VGPR 56). R15 64-tok/wave regressed (VGPR 100, occ
// 17%, scan 52.8) -> R16 reverts scan to R14 + fuses nb_reduce into merge.
// Scan VGPR knife-edge: 56 regs/31% occ is the measured local optimum.
// ---------------------------------------------------------------------------

#define N_TOK 16384
#define DIM   256
#define K_CB  4096

typedef _Float16 h8    __attribute__((ext_vector_type(8)));
typedef float    f32x4 __attribute__((ext_vector_type(4)));
typedef float    f32x16 __attribute__((ext_vector_type(16)));

// ---- ws layout (bytes) ----
#define WS_ZF      0u            // N_TOK * 512B fp16 frag layout = 8 MB
#define WS_CP      8388608u      // K_CB * 512B fp16 rows         = 2 MB
#define WS_CN      10485760u     // K_CB fp32 |c|^2               = 16 KB
#define WS_NRM     10502144u     // N_TOK float2                  = 128 KB
#define WS_CAND    10633216u     // N_TOK * 32 float2             = 4 MB
#define WS_COUNT   14827520u     // K_CB int                      = 16 KB
#define WS_SLOTS   14843904u     // K_CB * 1024 int               = 16 MB
#define WS_NACC    31621120u     // K_CB float                    = 16 KB
#define WS_LPART   31637520u     // 4096 float
#define WS_MPART   31653904u     // 4096 float
#define WS_NBPART  31670288u     // 1024 float2 = 8 KB

__device__ __forceinline__ void gload_lds16(const void* g, void* l) {
  __builtin_amdgcn_global_load_lds(
      (const __attribute__((address_space(1))) uint32_t*)g,
      (__attribute__((address_space(3))) uint32_t*)l, 16, 0, 0);
}

// ---- 1: fused split: blocks 0-2047 = z path, 2048-3071 = codebook path ----
__global__ void vq_split(const float* __restrict__ z, const float* __restrict__ cb,
                         unsigned short* __restrict__ zf, float2* __restrict__ nrm,
                         unsigned short* __restrict__ cp1, float* __restrict__ cn1,
                         float2* __restrict__ nbpart) {
  __shared__ float sm1[4], sm2[4];
  if (blockIdx.x < 2048) {
    // ---- z split: fragment-layout fp16 + per-token norms ----
    int t = blockIdx.x * 256 + threadIdx.x;     // 524288 threads, 32 per token
    int tok = t >> 5, c = t & 31;
    const float4* zp = reinterpret_cast<const float4*>(z) + (size_t)tok * 64 + c * 2;
    float4 va = zp[0], vb = zp[1];
    float x[8] = {va.x, va.y, va.z, va.w, vb.x, vb.y, vb.z, vb.w};
    union { _Float16 h[8]; uint4 u; } a;
    float s1 = 0.f, s2 = 0.f;
#pragma unroll
    for (int i = 0; i < 8; ++i) {
      _Float16 h1 = (_Float16)x[i];
      float lo = (x[i] - (float)h1) * 2048.0f;
      a.h[i] = h1;
      s1 += (float)h1 * (float)h1;
      s2 += lo * lo;
    }
    size_t off = (size_t)(tok >> 7) * 65536u + (size_t)(c >> 1) * 4096u
               + (size_t)(tok & 127) * 32u + (size_t)(c & 1) * 16u;
    *reinterpret_cast<uint4*>((unsigned char*)zf + off) = a.u;
#pragma unroll
    for (int o = 1; o < 32; o <<= 1) { s1 += __shfl_xor(s1, o); s2 += __shfl_xor(s2, o); }
    if (c == 0) nrm[tok] = make_float2(sqrtf(s1), sqrtf(s2));
  } else {
    // ---- codebook split: h1 rows + |c|^2 + per-block norm maxima ----
    int bid = blockIdx.x - 2048;
    int w = threadIdx.x >> 6, l = threadIdx.x & 63;
    int row = bid * 4 + w;
    float4 v = reinterpret_cast<const float4*>(cb)[row * 64 + l];
    float x[4] = {v.x, v.y, v.z, v.w};
    union { _Float16 h[4]; ushort4 u; } a;
    double ss = 0.0;
    float s1 = 0.f, s2 = 0.f;
#pragma unroll
    for (int i = 0; i < 4; ++i) {
      _Float16 h1 = (_Float16)x[i];
      float lo = (x[i] - (float)h1) * 2048.0f;
      a.h[i] = h1;
      s1 += (float)h1 * (float)h1;
      s2 += lo * lo;
      ss += (double)x[i] * (double)x[i];
    }
    reinterpret_cast<ushort4*>(cp1)[row * 64 + l] = a.u;
    for (int off = 1; off < 64; off <<= 1) {
      s1 += __shfl_xor(s1, off); s2 += __shfl_xor(s2, off); ss += __shfl_xor(ss, off);
    }
    if (l == 0) {
      cn1[row] = (float)ss;
      sm1[w] = s1; sm2[w] = s2;
    }
    __syncthreads();
    if (threadIdx.x == 0) {
      float m1 = fmaxf(fmaxf(sm1[0], sm1[1]), fmaxf(sm1[2], sm1[3]));
      float m2 = fmaxf(fmaxf(sm2[0], sm2[1]), fmaxf(sm2[2], sm2[3]));
      nbpart[bid] = make_float2(sqrtf(m1), sqrtf(m2));
    }
  }
}

// ---- 2: distance scan (R14 form: R12 structure + setprio) ------------------
// Block: 512 thr = 8 waves; wave w owns tokens tok0+w*32..+31 (Z in 64 VGPR).
// LDS (dynamic 66048B): CB slice 128 entries x 512B (XOR-32 chunk swizzle,
// pre-swizzled global src) + 128 fp32 norms. acc init = -0.5*(zn+cn) so
// acc = -d/2 <= 0 and min-uint(acc bits) = min-d; key = bits&~0xFF | eloc.
__global__ __launch_bounds__(512, 2) void vq_scan(
    const unsigned short* __restrict__ zf, const unsigned short* __restrict__ cp,
    const float* __restrict__ cn1, const float2* __restrict__ nrm,
    float2* __restrict__ cand) {
  extern __shared__ __align__(1024) unsigned char lds[];   // 66048 bytes
  unsigned char* cbl = lds;                                // 64 KB
  float* cnl = reinterpret_cast<float*>(lds + 65536);      // 512 B

  const int bid  = blockIdx.x;
  const int wgid = (bid & 7) * 256 + (bid >> 3);   // bijective: 2048 = 8*256
  const int tg   = wgid >> 5;                      // 0..63 token group (256 tok)
  const int es   = wgid & 31;                      // 0..31 entry split (128 e)
  const int tok0 = tg * 256;
  const int e0b  = es * 128;

  const int tx = threadIdx.x;
  const int w = tx >> 6, l = tx & 63;
  const int r = l & 31, h = l >> 5;

  // Z fragments: 16 x h8 = 64 VGPRs, volatile asm = forced resident (R9)
  const unsigned char* zg = (const unsigned char*)zf
      + (size_t)(tg * 2 + (w >> 2)) * 65536u
      + (unsigned)((((w & 3) * 32 + r) * 32) + h * 16);
  h8 zfr[16];
#pragma unroll
  for (int kt = 0; kt < 16; ++kt) {
    const void* p = zg + kt * 4096;
    asm volatile("global_load_dwordx4 %0, %1, off"
                 : "=v"(zfr[kt]) : "v"(p));
  }
  float znr = nrm[tok0 + w * 32 + r].x;
  const float zn = znr * znr;

  // stage whole CB slice (8 rounds x 8KB) + cn row; ONE barrier
  const unsigned char* cpb = (const unsigned char*)cp;
#pragma unroll
  for (int j = 0; j < 8; ++j) {
    int row = j * 16 + w * 2 + (l >> 5);           // each of 128 rows once
    int lc  = (l & 31) ^ (row & 31);               // logical chunk (swizzled)
    gload_lds16(cpb + (size_t)(e0b + row) * 512 + lc * 16,
                &cbl[(j * 16 + w * 2) * 512]);     // wave-uniform dst
  }
  if (tx < 32)
    gload_lds16((const unsigned char*)cn1 + (size_t)e0b * 4 + tx * 16, cnl);
  __syncthreads();   // vmcnt(0): CB slice + cn + zfr all landed

  unsigned lo = 0xFFFFFFFFu, hi = 0xFFFFFFFFu;
#pragma unroll
  for (int t = 0; t < 4; ++t) {
    f32x16 acc;
#pragma unroll
    for (int g = 0; g < 4; ++g) {
      f32x4 cnv = *reinterpret_cast<const f32x4*>(&cnl[t * 32 + g * 8 + 4 * h]);
#pragma unroll
      for (int q = 0; q < 4; ++q) acc[g * 4 + q] = -0.5f * (zn + cnv[q]);
    }
    __builtin_amdgcn_s_setprio(1);
#pragma unroll
    for (int kt = 0; kt < 16; ++kt) {
      int sc = (kt * 2 + h) ^ r;
      h8 af = *reinterpret_cast<const h8*>(&cbl[t * 16384 + r * 512 + sc * 16]);
      acc = __builtin_amdgcn_mfma_f32_32x32x16_f16(af, zfr[kt], acc, 0, 0, 0);
    }
    __builtin_amdgcn_s_setprio(0);
#pragma unroll
    for (int i = 0; i < 16; ++i) {
      unsigned eloc = (unsigned)(t * 32 + ((i & 3) + 8 * (i >> 2) + 4 * h));
      unsigned key = (__float_as_uint(acc[i]) & 0xFFFFFF00u) | eloc;
      unsigned mx = lo > key ? lo : key;
      lo = lo < key ? lo : key;
      hi = hi < mx ? hi : mx;
    }
  }

  // merge the two lane-halves, write one float2 record (keys in bits)
  {
    unsigned olo = __shfl_xor(lo, 32), ohi = __shfl_xor(hi, 32);
    unsigned mx = lo > olo ? lo : olo;
    lo = lo < olo ? lo : olo;
    hi = hi < ohi ? hi : ohi;
    hi = hi < mx ? hi : mx;
    if (h == 0) {
      int token = tok0 + w * 32 + r;
      cand[(size_t)token * 32 + es] =
          make_float2(__uint_as_float(lo), __uint_as_float(hi));
    }
  }
}

// ---- 3: fused nb-reduce + decode keys + exact fp64 rescore; bucket write ---
__global__ void vq_merge(
    const float2* __restrict__ cand, const float* __restrict__ z,
    const float* __restrict__ mask, const float* __restrict__ codebook,
    const float2* __restrict__ nrm, const float2* __restrict__ nbpart,
    float* __restrict__ out0, float* __restrict__ out_idx,
    int* __restrict__ count, int* __restrict__ slots,
    float* __restrict__ loss_part, float* __restrict__ mask_part) {
  __shared__ float ls[4], ms[4];
  __shared__ float nbs1[4], nbs2[4];
  int w = threadIdx.x >> 6, l = threadIdx.x & 63;
  int token = blockIdx.x * 4 + w;

  // fused nb max-reduce: 1024 float2, L2-resident (replaces 1-block kernel)
  {
    float m1 = 0.f, m2 = 0.f;
    for (int i = threadIdx.x; i < 1024; i += 256) {
      float2 p = nbpart[i];
      m1 = fmaxf(m1, p.x); m2 = fmaxf(m2, p.y);
    }
    for (int o = 1; o < 64; o <<= 1) {
      m1 = fmaxf(m1, __shfl_xor(m1, o));
      m2 = fmaxf(m2, __shfl_xor(m2, o));
    }
    if (l == 0) { nbs1[w] = m1; nbs2[w] = m2; }
  }

  float2 rec = cand[(size_t)token * 32 + (l & 31)];
  unsigned k1 = __float_as_uint(rec.x), k2 = __float_as_uint(rec.y);
  float rv1 = -2.0f * __uint_as_float(k1 & 0xFFFFFF00u);
  float rv2 = -2.0f * __uint_as_float(k2 & 0xFFFFFF00u);
  int   ri1 = (l & 31) * 128 + (int)(k1 & 0xFFu);
  int   ri2 = (l & 31) * 128 + (int)(k2 & 0xFFu);
  float m_a = rv1;
  for (int o = 1; o < 32; o <<= 1) m_a = fminf(m_a, __shfl_xor(m_a, o));

  __syncthreads();
  float NB1 = fmaxf(fmaxf(nbs1[0], nbs1[1]), fmaxf(nbs1[2], nbs1[3]));
  float NB2 = fmaxf(fmaxf(nbs2[0], nbs2[1]), fmaxf(nbs2[2], nbs2[3]));

  // rigorous fp16-GEMM error bound + key-truncation widening
  float2 nh = nrm[token];
  float E = 2.0f * ((nh.x * NB2 + nh.y * NB1) * (1.0f / 2048.0f)
                    + nh.y * NB2 * (1.0f / 4194304.0f));
  float thr = m_a * 1.0001f + 2.0f * E * 1.05f + 0.1f;

  float4 zv = reinterpret_cast<const float4*>(z)[(size_t)token * 64 + l];

  unsigned long long c1 = __ballot((l < 32) && (rv1 <= thr));
  unsigned long long c2 = __ballot((l < 32) && (rv2 <= thr));
  double bd = 1e300; int bi = 0x7fffffff;
  float4 cvb = make_float4(0.f, 0.f, 0.f, 0.f);
  while (c1 | c2) {
    int k;
    if (c1) { int s = __ffsll(c1) - 1; c1 &= c1 - 1; k = __shfl(ri1, s); }
    else    { int s = __ffsll(c2) - 1; c2 &= c2 - 1; k = __shfl(ri2, s); }
    float4 cv = reinterpret_cast<const float4*>(codebook)[(size_t)k * 64 + l];
    double d0 = (double)zv.x - cv.x, d1 = (double)zv.y - cv.y;
    double d2 = (double)zv.z - cv.z, d3 = (double)zv.w - cv.w;
    double dd = d0 * d0 + d1 * d1 + d2 * d2 + d3 * d3;
    for (int o = 1; o < 64; o <<= 1) dd += __shfl_xor(dd, o);
    if (dd < bd || (dd == bd && k < bi)) { bd = dd; bi = k; cvb = cv; }
  }

  reinterpret_cast<float4*>(out0)[(size_t)token * 64 + l] = cvb;  // quantized

  float mk = mask[token];
  if (l == 0) {
    out_idx[token] = (float)bi;
    int pos = atomicAdd(&count[bi], 1);            // cursor + histogram in one
    if (pos < 1024) slots[(size_t)bi * 1024 + pos] = token;
    ls[w] = mk * (float)bd * (1.0f / 256.0f);      // exact sum (z-q)^2
    ms[w] = mk;
  }
  __syncthreads();
  if (threadIdx.x == 0) {
    loss_part[blockIdx.x] = ls[0] + ls[1] + ls[2] + ls[3];
    mask_part[blockIdx.x] = ms[0] + ms[1] + ms[2] + ms[3];
  }
}

// ---- 4: segmented sum over slot rows: 8 waves/entry, 2-deep, LDS reduce ----
__global__ __launch_bounds__(512) void vq_segsum(
    const int* __restrict__ count, const int* __restrict__ slots,
    const float* __restrict__ z, const float* __restrict__ mask,
    const float* __restrict__ ew,
    float* __restrict__ out_weight, float* __restrict__ nacc) {
  __shared__ float4 red[8][64];
  __shared__ float nas[8];
  const int k = blockIdx.x;
  const int w = threadIdx.x >> 6, l = threadIdx.x & 63;
  int e = count[k]; if (e > 1024) e = 1024;
  const int* seg = slots + (size_t)k * 1024;
  const float4* z4 = reinterpret_cast<const float4*>(z);

  float ax = 0.f, ay = 0.f, az = 0.f, aw = 0.f, na = 0.f;
  int i = w;
  for (; i + 8 < e; i += 16) {
    int t0 = seg[i], t1 = seg[i + 8];
    float mk0 = mask[t0], mk1 = mask[t1];
    float4 a4 = z4[(size_t)t0 * 64 + l];
    float4 b4 = z4[(size_t)t1 * 64 + l];
    ax += mk0 * a4.x + mk1 * b4.x;
    ay += mk0 * a4.y + mk1 * b4.y;
    az += mk0 * a4.z + mk1 * b4.z;
    aw += mk0 * a4.w + mk1 * b4.w;
    na += mk0 + mk1;
  }
  if (i < e) {
    int t0 = seg[i];
    float mk0 = mask[t0];
    float4 a4 = z4[(size_t)t0 * 64 + l];
    ax += mk0 * a4.x; ay += mk0 * a4.y; az += mk0 * a4.z; aw += mk0 * a4.w;
    na += mk0;
  }
  red[w][l] = make_float4(ax, ay, az, aw);
  if (l == 0) nas[w] = na;
  __syncthreads();

  if (w == 0) {
    float4 a = red[0][l];
#pragma unroll
    for (int j = 1; j < 8; ++j) {
      float4 b = red[j][l];
      a.x += b.x; a.y += b.y; a.z += b.z; a.w += b.w;
    }
    float4 e4 = reinterpret_cast<const float4*>(ew)[(size_t)k * 64 + l];
    float4 o;
    o.x = 0.99f * e4.x + 0.01f * a.x;
    o.y = 0.99f * e4.y + 0.01f * a.y;
    o.z = 0.99f * e4.z + 0.01f * a.z;
    o.w = 0.99f * e4.w + 0.01f * a.w;
    reinterpret_cast<float4*>(out_weight)[(size_t)k * 64 + l] = o;
    if (l == 0) {
      float nn = 0.f;
#pragma unroll
      for (int j = 0; j < 8; ++j) nn += nas[j];
      nacc[k] = nn;
    }
  }
}

// ---- 5: new_count normalize + deterministic loss reduce --------------------
__global__ void vq_finish_count(const float* __restrict__ ec, const float* __restrict__ nacc,
                                const float* __restrict__ loss_part,
                                const float* __restrict__ mask_part,
                                float* __restrict__ out_count, float* __restrict__ out_loss) {
  __shared__ float nc_s[K_CB];
  __shared__ float red[256];
  int tid = threadIdx.x;
  float part = 0.f;
  for (int i = tid; i < K_CB; i += 256) {
    float nc = 0.99f * ec[i] + 0.01f * nacc[i];
    nc_s[i] = nc; part += nc;
  }
  red[tid] = part; __syncthreads();
  for (int s = 128; s > 0; s >>= 1) { if (tid < s) red[tid] += red[tid + s]; __syncthreads(); }
  float total = red[0];
  float scale = total / (total + (float)K_CB * 1e-5f);
  for (int i = tid; i < K_CB; i += 256) out_count[i] = (nc_s[i] + 1e-5f) * scale;
  __syncthreads();

  float ln = 0.f, lm = 0.f;
  for (int i = tid; i < 4096; i += 256) { ln += loss_part[i]; lm += mask_part[i]; }
  red[tid] = ln; __syncthreads();
  for (int s = 128; s > 0; s >>= 1) { if (tid < s) red[tid] += red[tid + s]; __syncthreads(); }
  ln = red[0]; __syncthreads();
  red[tid] = lm; __syncthreads();
  for (int s = 128; s > 0; s >>= 1) { if (tid < s) red[tid] += red[tid + s]; __syncthreads(); }
  lm = red[0];
  if (tid == 0) out_loss[0] = 2.5f * ln / lm;      // 10 * 0.25 * num/den
}

extern "C" void kernel_launch(void* const* d_in, const int* in_sizes, int n_in,
                              void* d_out, int out_size, void* d_ws, size_t ws_size,
                              hipStream_t stream) {
  const float* z          = (const float*)d_in[0];
  const float* mask       = (const float*)d_in[1];
  const float* codebook   = (const float*)d_in[2];
  const float* ema_count  = (const float*)d_in[3];
  const float* ema_weight = (const float*)d_in[4];

  float* out        = (float*)d_out;
  float* out0       = out;                         // 4194304
  float* out_idx    = out + 4194304;               // 16384
  float* out_loss   = out + 4210688;               // 1
  float* out_count  = out + 4210689;               // 4096
  float* out_weight = out + 4214785;               // 1048576

  char* ws = (char*)d_ws;
  unsigned short* zf  = (unsigned short*)(ws + WS_ZF);
  unsigned short* cp1 = (unsigned short*)(ws + WS_CP);
  float*  cn1    = (float*) (ws + WS_CN);
  float2* nrm    = (float2*)(ws + WS_NRM);
  float2* cand   = (float2*)(ws + WS_CAND);
  int*    count  = (int*)   (ws + WS_COUNT);
  int*    slots  = (int*)   (ws + WS_SLOTS);
  float*  nacc   = (float*) (ws + WS_NACC);
  float*  lpart  = (float*) (ws + WS_LPART);
  float*  mpart  = (float*) (ws + WS_MPART);
  float2* nbpart = (float2*)(ws + WS_NBPART);

  (void)hipFuncSetAttribute((const void*)vq_scan,
                            hipFuncAttributeMaxDynamicSharedMemorySize, 66048);
  (void)hipMemsetAsync(ws + WS_COUNT, 0, 16384, stream);   // count only

  vq_split<<<3072, 256, 0, stream>>>(z, codebook, zf, nrm, cp1, cn1, nbpart);
  vq_scan<<<2048, 512, 66048, stream>>>(zf, cp1, cn1, nrm, cand);
  vq_merge<<<4096, 256, 0, stream>>>(cand, z, mask, codebook, nrm, nbpart,
                                     out0, out_idx, count, slots, lpart, mpart);
  vq_segsum<<<4096, 512, 0, stream>>>(count, slots, z, mask, ema_weight,
                                      out_weight, nacc);
  vq_finish_count<<<1, 256, 0, stream>>>(ema_count, nacc, lpart, mpart,
                                         out_count, out_loss);
}